// Round 22
// baseline (140.597 us; speedup 1.0000x reference)
//
#include <hip/hip_runtime.h>

typedef unsigned short u16;
typedef __bf16 b16x8_t __attribute__((ext_vector_type(8)));
typedef unsigned short u16x8 __attribute__((ext_vector_type(8)));
typedef float f32x4 __attribute__((ext_vector_type(4)));
typedef float f32x16 __attribute__((ext_vector_type(16)));

__device__ __forceinline__ u16 f2bf(float f) {
  union { float f; unsigned u; } x; x.f = f;
  unsigned r = x.u + 0x7fffu + ((x.u >> 16) & 1u);
  return (u16)(r >> 16);
}

__device__ __forceinline__ f32x4 mfma16(u16x8 a, u16x8 b, f32x4 c) {
  return __builtin_amdgcn_mfma_f32_16x16x32_bf16(
      __builtin_bit_cast(b16x8_t, a), __builtin_bit_cast(b16x8_t, b), c, 0, 0, 0);
}

__device__ __forceinline__ f32x16 mfma32(u16x8 a, u16x8 b, f32x16 c) {
  return __builtin_amdgcn_mfma_f32_32x32x16_bf16(
      __builtin_bit_cast(b16x8_t, a), __builtin_bit_cast(b16x8_t, b), c, 0, 0, 0);
}

__device__ __forceinline__ void gld_lds16(const void* g, void* l) {
  __builtin_amdgcn_global_load_lds(
      (const __attribute__((address_space(1))) void*)g,
      (__attribute__((address_space(3))) void*)l, 16, 0, 0);
}

__device__ __forceinline__ void store_out(float* p, float v) { *p = v; }
__device__ __forceinline__ void store_out(u16* p, float v) { *p = f2bf(v); }

// ---------------- fused prep: convert x->bf16 + transpose Pi + transpose Po ---
__global__ __launch_bounds__(256) void prep(const float* __restrict__ x,
                                            u16* __restrict__ xbf,
                                            const float* __restrict__ Pi,
                                            u16* __restrict__ piT,
                                            const float* __restrict__ Po,
                                            u16* __restrict__ poT) {
  __shared__ float t[32][33];
  const int bid = blockIdx.x, tid = threadIdx.x;
  if (bid < 8192) {
    int i = bid * 256 + tid;
    float4 f = ((const float4*)x)[i];
    u16 a0 = f2bf(f.x), a1 = f2bf(f.y), a2 = f2bf(f.z), a3 = f2bf(f.w);
    unsigned lo = (unsigned)a0 | ((unsigned)a1 << 16);
    unsigned hi = (unsigned)a2 | ((unsigned)a3 << 16);
    ((uint2*)xbf)[i] = make_uint2(lo, hi);
    return;
  }
  const float* src; u16* dst; int R, Cn, bx, by;
  if (bid < 11264) {
    int tb = bid - 8192;  src = Pi; dst = piT; R = 1024; Cn = 3072;
    bx = tb % 96; by = tb / 96;
  } else {
    int tb = bid - 11264; src = Po; dst = poT; R = 1024; Cn = 1024;
    bx = tb % 32; by = tb / 32;
  }
  const int tx = tid & 31, ty = tid >> 5;
  const int c0 = bx * 32, r0 = by * 32;
  for (int j = 0; j < 32; j += 8)
    t[ty + j][tx] = src[(size_t)(r0 + ty + j) * Cn + c0 + tx];
  __syncthreads();
  for (int j = 0; j < 32; j += 8)
    dst[(size_t)(c0 + ty + j) * R + r0 + tx] = f2bf(t[tx][ty + j]);
}

// ---------------- GEMM1 (32x32x16 MFMA): qkv = xbf * piT^T, fused epilogue ----
// v7's converged schedule/staging/swizzle verbatim; only the MFMA shape and
// fragment/epilogue mappings change. Per-wave 64x96 = 2x3 tiles of 32x32
// (acc 6 x f32x16); per K-step 10 ds_read_b128 + 12 MFMA (vs 24 of 16x16:
// -17% matrix-pipe cycles at equal FLOPs, ubench 2382 vs 2075 TF).
// A/B frag: row = lane&31, k = (lane>>5)*8 (+8 per kh). C/D (m74/m101):
// col = lane&31, row = (reg&3) + 8*(reg>>2) + 4*(lane>>5).
__global__ __launch_bounds__(256, 2) void gemm32(const u16* __restrict__ A,
                                                 const u16* __restrict__ Bt,
                                                 u16* __restrict__ C,
                                                 u16* __restrict__ Vt,
                                                 int M, int N, int K) {
  __shared__ __align__(16) u16 sA[3][4096];
  __shared__ __align__(16) u16 sB[3][6144];
  const int tid = threadIdx.x, lane = tid & 63, wid = tid >> 6;
  const int l31 = lane & 31, l5 = lane >> 5;
  const int wm = (wid >> 1) * 64, wn = (wid & 1) * 96;

  const int gdx = gridDim.x;
  const int nwg = gdx * gridDim.y;
  int wg = blockIdx.y * gdx + blockIdx.x;
  wg = (wg & 7) * (nwg >> 3) + (wg >> 3);
  const int m0 = (wg / gdx) * 128;
  const int n0 = (wg % gdx) * 192;

  const int sr = tid >> 2;
  const int scsw = ((tid & 3) ^ ((tid >> 3) & 3)) * 8;
  const u16* srcA = A + (size_t)(m0 + sr) * K + scsw;
  const u16* srcB = Bt + (size_t)(n0 + sr) * K + scsw;
  const size_t K64 = (size_t)64 * K;

  auto stage = [&](int buf, int t) {
    const int k0 = t * 32;
    gld_lds16(srcA + k0, &sA[buf][tid * 8]);
    gld_lds16(srcA + K64 + k0, &sA[buf][2048 + tid * 8]);
    gld_lds16(srcB + k0, &sB[buf][tid * 8]);
    gld_lds16(srcB + K64 + k0, &sB[buf][2048 + tid * 8]);
    gld_lds16(srcB + 2 * K64 + k0, &sB[buf][4096 + tid * 8]);
  };

  // fragment offsets: row = tile + l31; source chunk kh*2 + l5; LDS slot =
  // chunk ^ ((row>>1)&3) = chunk ^ ((l31>>1)&3) (tile multiple of 32).
  const int sw = (l31 >> 1) & 3;
  int offA32[2][2], offB32[3][2];
#pragma unroll
  for (int mt = 0; mt < 2; ++mt)
#pragma unroll
    for (int kh = 0; kh < 2; ++kh)
      offA32[mt][kh] = (wm + mt * 32 + l31) * 32 + (((kh * 2 + l5) ^ sw) * 8);
#pragma unroll
  for (int nt = 0; nt < 3; ++nt)
#pragma unroll
    for (int kh = 0; kh < 2; ++kh)
      offB32[nt][kh] = (wn + nt * 32 + l31) * 32 + (((kh * 2 + l5) ^ sw) * 8);

  f32x16 acc[2][3] = {};
  const int NT = K >> 5;  // 32

  stage(0, 0); stage(1, 1);
  asm volatile("s_waitcnt vmcnt(5)" ::: "memory");
  __builtin_amdgcn_s_barrier();

  int cb = 0, sb = 2;
  for (int kt = 0; kt < NT; ++kt) {
    u16x8 af[2][2], bf[3][2];
#pragma unroll
    for (int mt = 0; mt < 2; ++mt)
#pragma unroll
      for (int kh = 0; kh < 2; ++kh)
        af[mt][kh] = *(const u16x8*)(&sA[cb][offA32[mt][kh]]);
#pragma unroll
    for (int nt = 0; nt < 3; ++nt)
#pragma unroll
      for (int kh = 0; kh < 2; ++kh)
        bf[nt][kh] = *(const u16x8*)(&sB[cb][offB32[nt][kh]]);
    if (kt + 2 < NT) {
      stage(sb, kt + 2);
      sb = (sb == 2) ? 0 : sb + 1;
      asm volatile("s_waitcnt vmcnt(5)" ::: "memory");
    } else {
      asm volatile("s_waitcnt vmcnt(0)" ::: "memory");
    }
    __builtin_amdgcn_s_barrier();
    asm volatile("s_waitcnt lgkmcnt(0)" ::: "memory");
    __builtin_amdgcn_sched_barrier(0);
    __builtin_amdgcn_s_setprio(1);
#pragma unroll
    for (int kh = 0; kh < 2; ++kh)
#pragma unroll
      for (int mt = 0; mt < 2; ++mt)
#pragma unroll
        for (int nt = 0; nt < 3; ++nt)
          acc[mt][nt] = mfma32(af[mt][kh], bf[nt][kh], acc[mt][nt]);
    __builtin_amdgcn_s_setprio(0);
    __builtin_amdgcn_sched_barrier(0);
    __builtin_amdgcn_s_barrier();
    cb = (cb == 2) ? 0 : cb + 1;
  }

  // epilogue: col = l31 (+tile), row = rbase + 8*(reg>>2) + (reg&3)
#pragma unroll
  for (int mt = 0; mt < 2; ++mt) {
    const int rbase = m0 + wm + mt * 32 + 4 * l5;
#pragma unroll
    for (int nt = 0; nt < 3; ++nt) {
      int colw = wn + nt * 32 + l31;       // region uniform per (wave, nt)
      if (colw >= 128) {
        int h = n0 / 192, kk = colw - 128;
#pragma unroll
        for (int g = 0; g < 4; ++g) {
          int row = rbase + 8 * g;
          int b = row >> 10, n = row & 1023;
          ushort4 pk;
          pk.x = f2bf(acc[mt][nt][4 * g + 0]);
          pk.y = f2bf(acc[mt][nt][4 * g + 1]);
          pk.z = f2bf(acc[mt][nt][4 * g + 2]);
          pk.w = f2bf(acc[mt][nt][4 * g + 3]);
          *(ushort4*)(Vt + ((size_t)(b * 16 + h) * 64 + kk) * 1024 + n) = pk;
        }
      } else {
        float sc = (colw < 64) ? 0.125f : 1.f;
        int col = n0 + colw;
#pragma unroll
        for (int g = 0; g < 4; ++g)
#pragma unroll
          for (int r2 = 0; r2 < 4; ++r2) {
            int row = rbase + 8 * g + r2;
            C[(size_t)row * N + col] = f2bf(acc[mt][nt][4 * g + r2] * sc);
          }
      }
    }
  }
}

// ---------------- bf16 GEMM v7 (GEMM2 only: BN=128, plain f32 epilogue) -------
template <typename OutT, int BN, int EPI>
__global__ __launch_bounds__(256, 2) void gemm_v7(const u16* __restrict__ A,
                                                  const u16* __restrict__ Bt,
                                                  OutT* __restrict__ C,
                                                  u16* __restrict__ Vt,
                                                  int M, int N, int K) {
  constexpr int NB = BN / 64;
  constexpr int NJ = BN / 32;
  constexpr int NL = 2 + NB;
  __shared__ __align__(16) u16 sA[3][4096];
  __shared__ __align__(16) u16 sB[3][BN * 32];
  const int tid = threadIdx.x, lane = tid & 63, wid = tid >> 6;
  const int hi = lane >> 4, ln = lane & 15;
  const int wm = (wid >> 1) * 64, wn = (wid & 1) * (BN / 2);

  const int gdx = gridDim.x;
  const int nwg = gdx * gridDim.y;
  int wg = blockIdx.y * gdx + blockIdx.x;
  wg = (wg & 7) * (nwg >> 3) + (wg >> 3);
  const int m0 = (wg / gdx) * 128;
  const int n0 = (wg % gdx) * BN;

  const int sr = tid >> 2;
  const int scsw = ((tid & 3) ^ ((tid >> 3) & 3)) * 8;
  const u16* srcA = A + (size_t)(m0 + sr) * K + scsw;
  const u16* srcB = Bt + (size_t)(n0 + sr) * K + scsw;
  const size_t K64 = (size_t)64 * K;

  auto stage = [&](int buf, int t) {
    const int k0 = t * 32;
    gld_lds16(srcA + k0, &sA[buf][tid * 8]);
    gld_lds16(srcA + K64 + k0, &sA[buf][2048 + tid * 8]);
    gld_lds16(srcB + k0, &sB[buf][tid * 8]);
    gld_lds16(srcB + K64 + k0, &sB[buf][2048 + tid * 8]);
    if (NB > 2) gld_lds16(srcB + 2 * K64 + k0, &sB[buf][4096 + tid * 8]);
  };

  const int csw = (hi ^ ((ln >> 1) & 3)) * 8;
  int offA[4], offB[NJ];
#pragma unroll
  for (int i = 0; i < 4; ++i) offA[i] = (wm + i * 16 + ln) * 32 + csw;
#pragma unroll
  for (int j = 0; j < NJ; ++j) offB[j] = (wn + j * 16 + ln) * 32 + csw;

  f32x4 acc[4][NJ] = {};
  const int NT = K >> 5;

  stage(0, 0); stage(1, 1);
  if constexpr (NL == 5) asm volatile("s_waitcnt vmcnt(5)" ::: "memory");
  else                   asm volatile("s_waitcnt vmcnt(4)" ::: "memory");
  __builtin_amdgcn_s_barrier();

  int cb = 0, sb = 2;
  for (int kt = 0; kt < NT; ++kt) {
    u16x8 af[4], bf[NJ];
#pragma unroll
    for (int i = 0; i < 4; ++i) af[i] = *(const u16x8*)(&sA[cb][offA[i]]);
#pragma unroll
    for (int j = 0; j < NJ; ++j) bf[j] = *(const u16x8*)(&sB[cb][offB[j]]);
    if (kt + 2 < NT) {
      stage(sb, kt + 2);
      sb = (sb == 2) ? 0 : sb + 1;
      if constexpr (NL == 5) asm volatile("s_waitcnt vmcnt(5)" ::: "memory");
      else                   asm volatile("s_waitcnt vmcnt(4)" ::: "memory");
    } else {
      asm volatile("s_waitcnt vmcnt(0)" ::: "memory");
    }
    __builtin_amdgcn_s_barrier();
    asm volatile("s_waitcnt lgkmcnt(0)" ::: "memory");
    __builtin_amdgcn_sched_barrier(0);
    __builtin_amdgcn_s_setprio(1);
#pragma unroll
    for (int i = 0; i < 4; ++i)
#pragma unroll
      for (int j = 0; j < NJ; ++j)
        acc[i][j] = mfma16(af[i], bf[j], acc[i][j]);
    __builtin_amdgcn_s_setprio(0);
    __builtin_amdgcn_sched_barrier(0);
    __builtin_amdgcn_s_barrier();
    cb = (cb == 2) ? 0 : cb + 1;
  }

#pragma unroll
  for (int i = 0; i < 4; ++i) {
    int rr = m0 + wm + i * 16 + hi * 4;
#pragma unroll
    for (int j = 0; j < NJ; ++j) {
      int colw = wn + j * 16 + ln;
      float sc = (EPI == 1 && colw < 64) ? 0.125f : 1.f;
      int col = n0 + colw;
#pragma unroll
      for (int r = 0; r < 4; ++r)
        store_out(&C[(size_t)(rr + r) * N + col], acc[i][j][r] * sc);
    }
  }
}

// ---------------- causal flash attention v7 (R20 exact): merged halves + XCD --
__global__ __launch_bounds__(512, 4) void attn_fwd7(const u16* __restrict__ QKV,
                                                    const u16* __restrict__ Vt,
                                                    u16* __restrict__ O) {
  __shared__ __align__(16) u16 sK[2][4096];
  __shared__ __align__(16) u16 sVt[2][4096];
  __shared__ __align__(16) u16 sP[8][16 * 72];
  const int tid = threadIdx.x, lane = tid & 63, wid = tid >> 6;
  const int bid = blockIdx.x;
  const int w = (bid & 7) * 64 + (bid >> 3);
  const int z = w & 3, h = (w >> 2) & 15, bb = w >> 6;
  const size_t rowbase = (size_t)bb * 1024;
  const size_t vbase = ((size_t)bb * 16 + h) * 64;
  const int colQ = h * 192, colK = colQ + 64;
  const int hi = lane >> 4, ln = lane & 15;
  const int slr = lane >> 3;
  const int sle = ((lane & 7) ^ slr) * 8;
  u16* sPw = sP[wid];
  const u16x8 onesf = {0x3F80, 0x3F80, 0x3F80, 0x3F80, 0x3F80, 0x3F80, 0x3F80, 0x3F80};

  auto stageKV = [&](int buf, int nt) {
    const int n0g = nt * 64;
    gld_lds16(QKV + (rowbase + n0g + 8 * wid + slr) * 3072 + colK + sle,
              &sK[buf][wid * 512]);
    gld_lds16(Vt + (vbase + 8 * wid + slr) * 1024 + n0g + sle,
              &sVt[buf][wid * 512]);
  };

  const int mtA = z, mtB = 7 - z;
  const int qrow0A = mtA * 128 + wid * 16;
  const int qrow0B = mtB * 128 + wid * 16;
  const int ntA = 2 * mtA + 2, ntB = 2 * mtB + 2;

  u16x8 qfA[2], qfB[2];
#pragma unroll
  for (int kb = 0; kb < 2; ++kb) {
    qfA[kb] = *(const u16x8*)(QKV + (rowbase + qrow0A + ln) * 3072 + colQ + kb * 32 + hi * 8);
    qfB[kb] = *(const u16x8*)(QKV + (rowbase + qrow0B + ln) * 3072 + colQ + kb * 32 + hi * 8);
  }

  f32x4 oA[4] = {}, oB[4] = {};
  f32x4 laccA = {0.f, 0.f, 0.f, 0.f}, laccB = {0.f, 0.f, 0.f, 0.f};

  auto computeHalf = [&](const u16x8* qf, f32x4* o, f32x4& lacc, int qrow0,
                         int buf, int n0g) {
    f32x4 s[4] = {};
    __builtin_amdgcn_s_setprio(1);
#pragma unroll
    for (int kb = 0; kb < 2; ++kb)
#pragma unroll
      for (int j = 0; j < 4; ++j) {
        int row = j * 16 + ln;
        int cb = (kb * 64 + hi * 16) ^ ((row & 7) << 4);
        u16x8 kfr = *(const u16x8*)(&sK[buf][(row * 128 + cb) >> 1]);
        s[j] = mfma16(qf[kb], kfr, s[j]);
      }
    __builtin_amdgcn_s_setprio(0);
    if (n0g + 63 > qrow0) {
#pragma unroll
      for (int j = 0; j < 4; ++j) {
        int col = n0g + j * 16 + ln;
#pragma unroll
        for (int r = 0; r < 4; ++r)
          if (col > qrow0 + hi * 4 + r) s[j][r] = -3e38f;
      }
    }
#pragma unroll
    for (int j = 0; j < 4; ++j)
#pragma unroll
      for (int r = 0; r < 4; ++r)
        sPw[(hi * 4 + r) * 72 + j * 16 + ln] = f2bf(__expf(s[j][r]));
    u16x8 pf[2];
#pragma unroll
    for (int kb2 = 0; kb2 < 2; ++kb2)
      pf[kb2] = *(const u16x8*)(&sPw[ln * 72 + kb2 * 32 + hi * 8]);
    __builtin_amdgcn_s_setprio(1);
    lacc = mfma16(pf[0], onesf, lacc);
    lacc = mfma16(pf[1], onesf, lacc);
#pragma unroll
    for (int dt = 0; dt < 4; ++dt)
#pragma unroll
      for (int kb2 = 0; kb2 < 2; ++kb2) {
        int row = dt * 16 + ln;
        int cb = (kb2 * 64 + hi * 16) ^ ((row & 7) << 4);
        u16x8 vfr = *(const u16x8*)(&sVt[buf][(row * 128 + cb) >> 1]);
        o[dt] = mfma16(pf[kb2], vfr, o[dt]);
      }
    __builtin_amdgcn_s_setprio(0);
  };

  stageKV(0, 0);
  for (int nt = 0; nt < ntB; ++nt) {
    __syncthreads();
    if (nt + 1 < ntB) stageKV((nt + 1) & 1, nt + 1);
    const int buf = nt & 1;
    const int n0g = nt * 64;
    if (nt < ntA && n0g <= qrow0A + 15) computeHalf(qfA, oA, laccA, qrow0A, buf, n0g);
    if (n0g <= qrow0B + 15)             computeHalf(qfB, oB, laccB, qrow0B, buf, n0g);
  }

#pragma unroll
  for (int r = 0; r < 4; ++r) {
    float invA = 1.f / laccA[r];
    float invB = 1.f / laccB[r];
#pragma unroll
    for (int dt = 0; dt < 4; ++dt) {
      O[(rowbase + qrow0A + hi * 4 + r) * 1024 + h * 64 + dt * 16 + ln] =
          f2bf(oA[dt][r] * invA);
      O[(rowbase + qrow0B + hi * 4 + r) * 1024 + h * 64 + dt * 16 + ln] =
          f2bf(oB[dt][r] * invB);
    }
  }
}

extern "C" void kernel_launch(void* const* d_in, const int* in_sizes, int n_in,
                              void* d_out, int out_size, void* d_ws, size_t ws_size,
                              hipStream_t stream) {
  const float* x = (const float*)d_in[0];
  const float* Pi = (const float*)d_in[1];
  const float* Po = (const float*)d_in[2];
  float* y = (float*)d_out;
  char* ws = (char*)d_ws;

  u16* qkv  = (u16*)(ws);                     // 0        .. 50331648
  u16* piT  = (u16*)(ws + 50331648);          // 50331648 .. 56623104
  u16* poT  = (u16*)(ws + 56623104);          // 56623104 .. 58720256
  u16* xbf  = (u16*)(ws + 58720256);          // 58720256 .. 75497472 (dead after GEMM1)
  u16* vt   = (u16*)(ws + 75497472);          // 75497472 .. 92274688
  u16* obuf = (u16*)(ws + 58720256);          // reuses xbf slot

  prep<<<12288, 256, 0, stream>>>(x, xbf, Pi, piT, Po, poT);

  gemm32<<<dim3(16, 64), 256, 0, stream>>>(xbf, piT, qkv, vt, 8192, 3072, 1024);
  attn_fwd7<<<512, 512, 0, stream>>>(qkv, vt, obuf);
  gemm_v7<float, 128, 0><<<dim3(8, 64), 256, 0, stream>>>(obuf, poT, y, nullptr,
                                                          8192, 1024, 1024);
}

// Round 23
// 132.854 us; speedup vs baseline: 1.0583x; 1.0583x over previous
//
#include <hip/hip_runtime.h>

typedef unsigned short u16;
typedef __bf16 b16x8_t __attribute__((ext_vector_type(8)));
typedef unsigned short u16x8 __attribute__((ext_vector_type(8)));
typedef float f32x4 __attribute__((ext_vector_type(4)));

__device__ __forceinline__ u16 f2bf(float f) {
  union { float f; unsigned u; } x; x.f = f;
  unsigned r = x.u + 0x7fffu + ((x.u >> 16) & 1u);
  return (u16)(r >> 16);
}

__device__ __forceinline__ f32x4 mfma16(u16x8 a, u16x8 b, f32x4 c) {
  return __builtin_amdgcn_mfma_f32_16x16x32_bf16(
      __builtin_bit_cast(b16x8_t, a), __builtin_bit_cast(b16x8_t, b), c, 0, 0, 0);
}

__device__ __forceinline__ void gld_lds16(const void* g, void* l) {
  __builtin_amdgcn_global_load_lds(
      (const __attribute__((address_space(1))) void*)g,
      (__attribute__((address_space(3))) void*)l, 16, 0, 0);
}

__device__ __forceinline__ void store_out(float* p, float v) { *p = v; }
__device__ __forceinline__ void store_out(u16* p, float v) { *p = f2bf(v); }

// ---------------- fused prep: convert x->bf16 + transpose Pi + transpose Po ---
// One launch replaces three serialized memory-bound kernels.
__global__ __launch_bounds__(256) void prep(const float* __restrict__ x,
                                            u16* __restrict__ xbf,
                                            const float* __restrict__ Pi,
                                            u16* __restrict__ piT,
                                            const float* __restrict__ Po,
                                            u16* __restrict__ poT) {
  __shared__ float t[32][33];
  const int bid = blockIdx.x, tid = threadIdx.x;
  if (bid < 8192) {
    int i = bid * 256 + tid;
    float4 f = ((const float4*)x)[i];
    u16 a0 = f2bf(f.x), a1 = f2bf(f.y), a2 = f2bf(f.z), a3 = f2bf(f.w);
    unsigned lo = (unsigned)a0 | ((unsigned)a1 << 16);
    unsigned hi = (unsigned)a2 | ((unsigned)a3 << 16);
    ((uint2*)xbf)[i] = make_uint2(lo, hi);
    return;
  }
  const float* src; u16* dst; int R, Cn, bx, by;
  if (bid < 11264) {
    int tb = bid - 8192;  src = Pi; dst = piT; R = 1024; Cn = 3072;
    bx = tb % 96; by = tb / 96;
  } else {
    int tb = bid - 11264; src = Po; dst = poT; R = 1024; Cn = 1024;
    bx = tb % 32; by = tb / 32;
  }
  const int tx = tid & 31, ty = tid >> 5;      // (32,8)
  const int c0 = bx * 32, r0 = by * 32;
  for (int j = 0; j < 32; j += 8)
    t[ty + j][tx] = src[(size_t)(r0 + ty + j) * Cn + c0 + tx];
  __syncthreads();
  for (int j = 0; j < 32; j += 8)
    dst[(size_t)(c0 + ty + j) * R + r0 + tx] = f2bf(t[tx][ty + j]);
}

// ---------------- bf16 GEMM v7: C[M][N] = A[M][K] * Bt[N][K]^T ----------------
// CONVERGED (13 variants incl. MFMA-shape swap: all 75+-2us; barrier-pace
// bound). Explicit vmcnt(counted)+barrier+lgkm(0)+fenced-MFMA is load-bearing.
// EPI=1: Q cols scaled 0.125; V cols written DIRECTLY TRANSPOSED to Vt.
template <typename OutT, int BN, int EPI>
__global__ __launch_bounds__(256, 2) void gemm_v7(const u16* __restrict__ A,
                                                  const u16* __restrict__ Bt,
                                                  OutT* __restrict__ C,
                                                  u16* __restrict__ Vt,
                                                  int M, int N, int K) {
  constexpr int NB = BN / 64;
  constexpr int NJ = BN / 32;
  constexpr int NL = 2 + NB;
  __shared__ __align__(16) u16 sA[3][4096];
  __shared__ __align__(16) u16 sB[3][BN * 32];
  const int tid = threadIdx.x, lane = tid & 63, wid = tid >> 6;
  const int hi = lane >> 4, ln = lane & 15;
  const int wm = (wid >> 1) * 64, wn = (wid & 1) * (BN / 2);

  const int gdx = gridDim.x;
  const int nwg = gdx * gridDim.y;
  int wg = blockIdx.y * gdx + blockIdx.x;
  wg = (wg & 7) * (nwg >> 3) + (wg >> 3);
  const int m0 = (wg / gdx) * 128;
  const int n0 = (wg % gdx) * BN;

  const int sr = tid >> 2;
  const int scsw = ((tid & 3) ^ ((tid >> 3) & 3)) * 8;
  const u16* srcA = A + (size_t)(m0 + sr) * K + scsw;
  const u16* srcB = Bt + (size_t)(n0 + sr) * K + scsw;
  const size_t K64 = (size_t)64 * K;

  auto stage = [&](int buf, int t) {
    const int k0 = t * 32;
    gld_lds16(srcA + k0, &sA[buf][tid * 8]);
    gld_lds16(srcA + K64 + k0, &sA[buf][2048 + tid * 8]);
    gld_lds16(srcB + k0, &sB[buf][tid * 8]);
    gld_lds16(srcB + K64 + k0, &sB[buf][2048 + tid * 8]);
    if (NB > 2) gld_lds16(srcB + 2 * K64 + k0, &sB[buf][4096 + tid * 8]);
  };

  const int csw = (hi ^ ((ln >> 1) & 3)) * 8;
  int offA[4], offB[NJ];
#pragma unroll
  for (int i = 0; i < 4; ++i) offA[i] = (wm + i * 16 + ln) * 32 + csw;
#pragma unroll
  for (int j = 0; j < NJ; ++j) offB[j] = (wn + j * 16 + ln) * 32 + csw;

  f32x4 acc[4][NJ] = {};
  const int NT = K >> 5;

  stage(0, 0); stage(1, 1);
  if constexpr (NL == 5) asm volatile("s_waitcnt vmcnt(5)" ::: "memory");
  else                   asm volatile("s_waitcnt vmcnt(4)" ::: "memory");
  __builtin_amdgcn_s_barrier();

  int cb = 0, sb = 2;
  for (int kt = 0; kt < NT; ++kt) {
    u16x8 af[4], bf[NJ];
#pragma unroll
    for (int i = 0; i < 4; ++i) af[i] = *(const u16x8*)(&sA[cb][offA[i]]);
#pragma unroll
    for (int j = 0; j < NJ; ++j) bf[j] = *(const u16x8*)(&sB[cb][offB[j]]);
    if (kt + 2 < NT) {
      stage(sb, kt + 2);
      sb = (sb == 2) ? 0 : sb + 1;
      if constexpr (NL == 5) asm volatile("s_waitcnt vmcnt(5)" ::: "memory");
      else                   asm volatile("s_waitcnt vmcnt(4)" ::: "memory");
    } else {
      asm volatile("s_waitcnt vmcnt(0)" ::: "memory");
    }
    __builtin_amdgcn_s_barrier();
    asm volatile("s_waitcnt lgkmcnt(0)" ::: "memory");
    __builtin_amdgcn_sched_barrier(0);
    __builtin_amdgcn_s_setprio(1);
#pragma unroll
    for (int i = 0; i < 4; ++i)
#pragma unroll
      for (int j = 0; j < NJ; ++j)
        acc[i][j] = mfma16(af[i], bf[j], acc[i][j]);
    __builtin_amdgcn_s_setprio(0);
    __builtin_amdgcn_sched_barrier(0);
    __builtin_amdgcn_s_barrier();
    cb = (cb == 2) ? 0 : cb + 1;
  }

#pragma unroll
  for (int i = 0; i < 4; ++i) {
    int rr = m0 + wm + i * 16 + hi * 4;
#pragma unroll
    for (int j = 0; j < NJ; ++j) {
      int colw = wn + j * 16 + ln;
      if (EPI == 1 && colw >= 128) {
        int h = n0 / 192, kk = colw - 128;
        int b = rr >> 10, n = rr & 1023;
        ushort4 pk;
        pk.x = f2bf(acc[i][j][0]); pk.y = f2bf(acc[i][j][1]);
        pk.z = f2bf(acc[i][j][2]); pk.w = f2bf(acc[i][j][3]);
        *(ushort4*)(Vt + ((size_t)(b * 16 + h) * 64 + kk) * 1024 + n) = pk;
      } else {
        float sc = (EPI == 1 && colw < 64) ? 0.125f : 1.f;
        int col = n0 + colw;
#pragma unroll
        for (int r = 0; r < 4; ++r)
          store_out(&C[(size_t)(rr + r) * N + col], acc[i][j][r] * sc);
      }
    }
  }
}

// ---------------- causal flash attention v7: merged halves + XCD KV locality --
__global__ __launch_bounds__(512, 4) void attn_fwd7(const u16* __restrict__ QKV,
                                                    const u16* __restrict__ Vt,
                                                    u16* __restrict__ O) {
  __shared__ __align__(16) u16 sK[2][4096];
  __shared__ __align__(16) u16 sVt[2][4096];
  __shared__ __align__(16) u16 sP[8][16 * 72];
  const int tid = threadIdx.x, lane = tid & 63, wid = tid >> 6;
  const int bid = blockIdx.x;                       // 0..511
  const int w = (bid & 7) * 64 + (bid >> 3);        // bijective (512 % 8 == 0)
  const int z = w & 3, h = (w >> 2) & 15, bb = w >> 6;
  const size_t rowbase = (size_t)bb * 1024;
  const size_t vbase = ((size_t)bb * 16 + h) * 64;
  const int colQ = h * 192, colK = colQ + 64;
  const int hi = lane >> 4, ln = lane & 15;
  const int slr = lane >> 3;
  const int sle = ((lane & 7) ^ slr) * 8;
  u16* sPw = sP[wid];
  const u16x8 onesf = {0x3F80, 0x3F80, 0x3F80, 0x3F80, 0x3F80, 0x3F80, 0x3F80, 0x3F80};

  auto stageKV = [&](int buf, int nt) {
    const int n0g = nt * 64;
    gld_lds16(QKV + (rowbase + n0g + 8 * wid + slr) * 3072 + colK + sle,
              &sK[buf][wid * 512]);
    gld_lds16(Vt + (vbase + 8 * wid + slr) * 1024 + n0g + sle,
              &sVt[buf][wid * 512]);
  };

  const int mtA = z, mtB = 7 - z;
  const int qrow0A = mtA * 128 + wid * 16;
  const int qrow0B = mtB * 128 + wid * 16;
  const int ntA = 2 * mtA + 2, ntB = 2 * mtB + 2;

  u16x8 qfA[2], qfB[2];
#pragma unroll
  for (int kb = 0; kb < 2; ++kb) {
    qfA[kb] = *(const u16x8*)(QKV + (rowbase + qrow0A + ln) * 3072 + colQ + kb * 32 + hi * 8);
    qfB[kb] = *(const u16x8*)(QKV + (rowbase + qrow0B + ln) * 3072 + colQ + kb * 32 + hi * 8);
  }

  f32x4 oA[4] = {}, oB[4] = {};
  f32x4 laccA = {0.f, 0.f, 0.f, 0.f}, laccB = {0.f, 0.f, 0.f, 0.f};

  auto computeHalf = [&](const u16x8* qf, f32x4* o, f32x4& lacc, int qrow0,
                         int buf, int n0g) {
    f32x4 s[4] = {};
    __builtin_amdgcn_s_setprio(1);
#pragma unroll
    for (int kb = 0; kb < 2; ++kb)
#pragma unroll
      for (int j = 0; j < 4; ++j) {
        int row = j * 16 + ln;
        int cb = (kb * 64 + hi * 16) ^ ((row & 7) << 4);
        u16x8 kfr = *(const u16x8*)(&sK[buf][(row * 128 + cb) >> 1]);
        s[j] = mfma16(qf[kb], kfr, s[j]);
      }
    __builtin_amdgcn_s_setprio(0);
    if (n0g + 63 > qrow0) {
#pragma unroll
      for (int j = 0; j < 4; ++j) {
        int col = n0g + j * 16 + ln;
#pragma unroll
        for (int r = 0; r < 4; ++r)
          if (col > qrow0 + hi * 4 + r) s[j][r] = -3e38f;
      }
    }
#pragma unroll
    for (int j = 0; j < 4; ++j)
#pragma unroll
      for (int r = 0; r < 4; ++r)
        sPw[(hi * 4 + r) * 72 + j * 16 + ln] = f2bf(__expf(s[j][r]));
    u16x8 pf[2];
#pragma unroll
    for (int kb2 = 0; kb2 < 2; ++kb2)
      pf[kb2] = *(const u16x8*)(&sPw[ln * 72 + kb2 * 32 + hi * 8]);
    __builtin_amdgcn_s_setprio(1);
    lacc = mfma16(pf[0], onesf, lacc);
    lacc = mfma16(pf[1], onesf, lacc);
#pragma unroll
    for (int dt = 0; dt < 4; ++dt)
#pragma unroll
      for (int kb2 = 0; kb2 < 2; ++kb2) {
        int row = dt * 16 + ln;
        int cb = (kb2 * 64 + hi * 16) ^ ((row & 7) << 4);
        u16x8 vfr = *(const u16x8*)(&sVt[buf][(row * 128 + cb) >> 1]);
        o[dt] = mfma16(pf[kb2], vfr, o[dt]);
      }
    __builtin_amdgcn_s_setprio(0);
  };

  stageKV(0, 0);
  for (int nt = 0; nt < ntB; ++nt) {
    __syncthreads();
    if (nt + 1 < ntB) stageKV((nt + 1) & 1, nt + 1);
    const int buf = nt & 1;
    const int n0g = nt * 64;
    if (nt < ntA && n0g <= qrow0A + 15) computeHalf(qfA, oA, laccA, qrow0A, buf, n0g);
    if (n0g <= qrow0B + 15)             computeHalf(qfB, oB, laccB, qrow0B, buf, n0g);
  }

#pragma unroll
  for (int r = 0; r < 4; ++r) {
    float invA = 1.f / laccA[r];
    float invB = 1.f / laccB[r];
#pragma unroll
    for (int dt = 0; dt < 4; ++dt) {
      O[(rowbase + qrow0A + hi * 4 + r) * 1024 + h * 64 + dt * 16 + ln] =
          f2bf(oA[dt][r] * invA);
      O[(rowbase + qrow0B + hi * 4 + r) * 1024 + h * 64 + dt * 16 + ln] =
          f2bf(oB[dt][r] * invB);
    }
  }
}

extern "C" void kernel_launch(void* const* d_in, const int* in_sizes, int n_in,
                              void* d_out, int out_size, void* d_ws, size_t ws_size,
                              hipStream_t stream) {
  const float* x = (const float*)d_in[0];
  const float* Pi = (const float*)d_in[1];
  const float* Po = (const float*)d_in[2];
  float* y = (float*)d_out;
  char* ws = (char*)d_ws;

  u16* qkv  = (u16*)(ws);                     // 0        .. 50331648
  u16* piT  = (u16*)(ws + 50331648);          // 50331648 .. 56623104
  u16* poT  = (u16*)(ws + 56623104);          // 56623104 .. 58720256
  u16* xbf  = (u16*)(ws + 58720256);          // 58720256 .. 75497472 (dead after GEMM1)
  u16* vt   = (u16*)(ws + 75497472);          // 75497472 .. 92274688
  u16* obuf = (u16*)(ws + 58720256);          // reuses xbf slot

  prep<<<12288, 256, 0, stream>>>(x, xbf, Pi, piT, Po, poT);

  gemm_v7<u16, 192, 1><<<dim3(16, 64), 256, 0, stream>>>(xbf, piT, qkv, vt,
                                                         8192, 3072, 1024);
  attn_fwd7<<<512, 512, 0, stream>>>(qkv, vt, obuf);
  gemm_v7<float, 128, 0><<<dim3(8, 64), 256, 0, stream>>>(obuf, poT, y, nullptr,
                                                          8192, 1024, 1024);
}

// Round 24
// 128.902 us; speedup vs baseline: 1.0907x; 1.0307x over previous
//
#include <hip/hip_runtime.h>

typedef unsigned short u16;
typedef __bf16 b16x8_t __attribute__((ext_vector_type(8)));
typedef unsigned short u16x8 __attribute__((ext_vector_type(8)));
typedef float f32x4 __attribute__((ext_vector_type(4)));

__device__ __forceinline__ u16 f2bf(float f) {
  union { float f; unsigned u; } x; x.f = f;
  unsigned r = x.u + 0x7fffu + ((x.u >> 16) & 1u);
  return (u16)(r >> 16);
}

__device__ __forceinline__ f32x4 mfma16(u16x8 a, u16x8 b, f32x4 c) {
  return __builtin_amdgcn_mfma_f32_16x16x32_bf16(
      __builtin_bit_cast(b16x8_t, a), __builtin_bit_cast(b16x8_t, b), c, 0, 0, 0);
}

__device__ __forceinline__ void gld_lds16(const void* g, void* l) {
  __builtin_amdgcn_global_load_lds(
      (const __attribute__((address_space(1))) void*)g,
      (__attribute__((address_space(3))) void*)l, 16, 0, 0);
}

__device__ __forceinline__ void store_out(float* p, float v) { *p = v; }
__device__ __forceinline__ void store_out(u16* p, float v) { *p = f2bf(v); }

// ---------------- fused prep: convert x->bf16 + transpose Pi + transpose Po ---
__global__ __launch_bounds__(256) void prep(const float* __restrict__ x,
                                            u16* __restrict__ xbf,
                                            const float* __restrict__ Pi,
                                            u16* __restrict__ piT,
                                            const float* __restrict__ Po,
                                            u16* __restrict__ poT) {
  __shared__ float t[32][33];
  const int bid = blockIdx.x, tid = threadIdx.x;
  if (bid < 8192) {
    int i = bid * 256 + tid;
    float4 f = ((const float4*)x)[i];
    u16 a0 = f2bf(f.x), a1 = f2bf(f.y), a2 = f2bf(f.z), a3 = f2bf(f.w);
    unsigned lo = (unsigned)a0 | ((unsigned)a1 << 16);
    unsigned hi = (unsigned)a2 | ((unsigned)a3 << 16);
    ((uint2*)xbf)[i] = make_uint2(lo, hi);
    return;
  }
  const float* src; u16* dst; int R, Cn, bx, by;
  if (bid < 11264) {
    int tb = bid - 8192;  src = Pi; dst = piT; R = 1024; Cn = 3072;
    bx = tb % 96; by = tb / 96;
  } else {
    int tb = bid - 11264; src = Po; dst = poT; R = 1024; Cn = 1024;
    bx = tb % 32; by = tb / 32;
  }
  const int tx = tid & 31, ty = tid >> 5;
  const int c0 = bx * 32, r0 = by * 32;
  for (int j = 0; j < 32; j += 8)
    t[ty + j][tx] = src[(size_t)(r0 + ty + j) * Cn + c0 + tx];
  __syncthreads();
  for (int j = 0; j < 32; j += 8)
    dst[(size_t)(c0 + ty + j) * R + r0 + tx] = f2bf(t[tx][ty + j]);
}

// ---------------- GEMM1 BK=64 ping-pong: ONE barrier + ONE drain per K-64 -----
// Thesis: 13 variants prove barrier-pace-bound (R22: half the MFMA instrs =
// same 75us). This halves sync events 4x: v7 = 4 barriers + 2 vm-drains per
// K-64-span; here = 1 + 1. 2 x 80KB LDS = exactly 160KB/CU -> 2 blocks/CU.
// Stage(kt+1) issued FIRST each iter; its HBM latency hides under the ~2x
// compute window (20 ds_read + 48 MFMA), making end-of-iter vmcnt(0) cheap.
// WAR: other-buf reads drained (lgkm0) before the barrier preceding its
// staging. RAW: per-wave vmcnt(0) precedes the shared barrier. Swizzle:
// LDS[r][c] = global[r][c^(r&7)] via pre-swizzled source; frag slot =
// (s*4+hi)^(ln&7); <=2-way bank aliasing (free, m136).
// Epilogue = v7 EPI=1: Q cols x0.125; V cols written transposed to Vt.
__global__ __launch_bounds__(256) void gemm_bk64(const u16* __restrict__ A,
                                                 const u16* __restrict__ Bt,
                                                 u16* __restrict__ C,
                                                 u16* __restrict__ Vt,
                                                 int M, int N, int K) {
  __shared__ __align__(16) u16 sA[2][8192];    // [buf][128 rows x 64 k]
  __shared__ __align__(16) u16 sB[2][12288];   // [buf][192 rows x 64 k]
  const int tid = threadIdx.x, lane = tid & 63, wid = tid >> 6;
  const int hi = lane >> 4, ln = lane & 15;
  const int wm = (wid >> 1) * 64, wn = (wid & 1) * 96;

  const int gdx = gridDim.x;
  const int nwg = gdx * gridDim.y;
  int wg = blockIdx.y * gdx + blockIdx.x;
  wg = (wg & 7) * (nwg >> 3) + (wg >> 3);
  const int m0 = (wg / gdx) * 128;
  const int n0 = (wg % gdx) * 192;

  // staging: per gld covers 32 rows; row = g*32 + (tid>>3), chunk-slot tid&7;
  // source chunk pre-swizzled by row&7 (= (tid>>3)&7 since g*32 is 8-aligned)
  const int sr = tid >> 3;
  const int ssw = ((tid & 7) ^ (sr & 7)) * 8;
  const u16* srcA = A + (size_t)(m0 + sr) * K + ssw;
  const u16* srcB = Bt + (size_t)(n0 + sr) * K + ssw;
  const size_t K32 = (size_t)32 * K;

  auto stage = [&](int buf, int t) {
    const int k0 = t * 64;
#pragma unroll
    for (int g = 0; g < 4; ++g)
      gld_lds16(srcA + (size_t)g * K32 + k0, &sA[buf][g * 2048 + tid * 8]);
#pragma unroll
    for (int g = 0; g < 6; ++g)
      gld_lds16(srcB + (size_t)g * K32 + k0, &sB[buf][g * 2048 + tid * 8]);
  };

  // fragment offsets: row*64 + ((s*4+hi) ^ (row&7))*8, row&7 == ln&7
  int offA[4][2], offB[6][2];
#pragma unroll
  for (int i = 0; i < 4; ++i) {
    int row = wm + i * 16 + ln;
#pragma unroll
    for (int s = 0; s < 2; ++s)
      offA[i][s] = row * 64 + (((s * 4 + hi) ^ (ln & 7)) * 8);
  }
#pragma unroll
  for (int j = 0; j < 6; ++j) {
    int row = wn + j * 16 + ln;
#pragma unroll
    for (int s = 0; s < 2; ++s)
      offB[j][s] = row * 64 + (((s * 4 + hi) ^ (ln & 7)) * 8);
  }

  f32x4 acc[4][6] = {};
  const int NT = K >> 6;  // 16

  stage(0, 0);
  asm volatile("s_waitcnt vmcnt(0)" ::: "memory");
  __builtin_amdgcn_s_barrier();

  for (int kt = 0; kt < NT; ++kt) {
    const int cb = kt & 1;
    if (kt + 1 < NT) stage(cb ^ 1, kt + 1);   // early issue; latency spans iter
#pragma unroll
    for (int s = 0; s < 2; ++s) {
      u16x8 af[4], bf[6];
#pragma unroll
      for (int i = 0; i < 4; ++i) af[i] = *(const u16x8*)(&sA[cb][offA[i][s]]);
#pragma unroll
      for (int j = 0; j < 6; ++j) bf[j] = *(const u16x8*)(&sB[cb][offB[j][s]]);
      asm volatile("s_waitcnt lgkmcnt(0)" ::: "memory");
      __builtin_amdgcn_sched_barrier(0);
      __builtin_amdgcn_s_setprio(1);
#pragma unroll
      for (int i = 0; i < 4; ++i)
#pragma unroll
        for (int j = 0; j < 6; ++j)
          acc[i][j] = mfma16(af[i], bf[j], acc[i][j]);
      __builtin_amdgcn_s_setprio(0);
      __builtin_amdgcn_sched_barrier(0);
    }
    asm volatile("s_waitcnt vmcnt(0)" ::: "memory");   // tile kt+1 landed
    __builtin_amdgcn_s_barrier();                      // the ONE barrier
  }

  // epilogue (v7 EPI=1): col = lane&15, row = (lane>>4)*4 + reg
#pragma unroll
  for (int i = 0; i < 4; ++i) {
    int rr = m0 + wm + i * 16 + hi * 4;
#pragma unroll
    for (int j = 0; j < 6; ++j) {
      int colw = wn + j * 16 + ln;
      if (colw >= 128) {
        int h = n0 / 192, kk = colw - 128;
        int b = rr >> 10, n = rr & 1023;
        ushort4 pk;
        pk.x = f2bf(acc[i][j][0]); pk.y = f2bf(acc[i][j][1]);
        pk.z = f2bf(acc[i][j][2]); pk.w = f2bf(acc[i][j][3]);
        *(ushort4*)(Vt + ((size_t)(b * 16 + h) * 64 + kk) * 1024 + n) = pk;
      } else {
        float sc = (colw < 64) ? 0.125f : 1.f;
        int col = n0 + colw;
#pragma unroll
        for (int r = 0; r < 4; ++r)
          C[(size_t)(rr + r) * N + col] = f2bf(acc[i][j][r] * sc);
      }
    }
  }
}

// ---------------- bf16 GEMM v7 (GEMM2: BN=128, plain f32 epilogue) ------------
template <typename OutT, int BN, int EPI>
__global__ __launch_bounds__(256, 2) void gemm_v7(const u16* __restrict__ A,
                                                  const u16* __restrict__ Bt,
                                                  OutT* __restrict__ C,
                                                  u16* __restrict__ Vt,
                                                  int M, int N, int K) {
  constexpr int NB = BN / 64;
  constexpr int NJ = BN / 32;
  constexpr int NL = 2 + NB;
  __shared__ __align__(16) u16 sA[3][4096];
  __shared__ __align__(16) u16 sB[3][BN * 32];
  const int tid = threadIdx.x, lane = tid & 63, wid = tid >> 6;
  const int hi = lane >> 4, ln = lane & 15;
  const int wm = (wid >> 1) * 64, wn = (wid & 1) * (BN / 2);

  const int gdx = gridDim.x;
  const int nwg = gdx * gridDim.y;
  int wg = blockIdx.y * gdx + blockIdx.x;
  wg = (wg & 7) * (nwg >> 3) + (wg >> 3);
  const int m0 = (wg / gdx) * 128;
  const int n0 = (wg % gdx) * BN;

  const int sr = tid >> 2;
  const int scsw = ((tid & 3) ^ ((tid >> 3) & 3)) * 8;
  const u16* srcA = A + (size_t)(m0 + sr) * K + scsw;
  const u16* srcB = Bt + (size_t)(n0 + sr) * K + scsw;
  const size_t K64 = (size_t)64 * K;

  auto stage = [&](int buf, int t) {
    const int k0 = t * 32;
    gld_lds16(srcA + k0, &sA[buf][tid * 8]);
    gld_lds16(srcA + K64 + k0, &sA[buf][2048 + tid * 8]);
    gld_lds16(srcB + k0, &sB[buf][tid * 8]);
    gld_lds16(srcB + K64 + k0, &sB[buf][2048 + tid * 8]);
    if (NB > 2) gld_lds16(srcB + 2 * K64 + k0, &sB[buf][4096 + tid * 8]);
  };

  const int csw = (hi ^ ((ln >> 1) & 3)) * 8;
  int offA[4], offB[NJ];
#pragma unroll
  for (int i = 0; i < 4; ++i) offA[i] = (wm + i * 16 + ln) * 32 + csw;
#pragma unroll
  for (int j = 0; j < NJ; ++j) offB[j] = (wn + j * 16 + ln) * 32 + csw;

  f32x4 acc[4][NJ] = {};
  const int NT = K >> 5;

  stage(0, 0); stage(1, 1);
  if constexpr (NL == 5) asm volatile("s_waitcnt vmcnt(5)" ::: "memory");
  else                   asm volatile("s_waitcnt vmcnt(4)" ::: "memory");
  __builtin_amdgcn_s_barrier();

  int cb = 0, sb = 2;
  for (int kt = 0; kt < NT; ++kt) {
    u16x8 af[4], bf[NJ];
#pragma unroll
    for (int i = 0; i < 4; ++i) af[i] = *(const u16x8*)(&sA[cb][offA[i]]);
#pragma unroll
    for (int j = 0; j < NJ; ++j) bf[j] = *(const u16x8*)(&sB[cb][offB[j]]);
    if (kt + 2 < NT) {
      stage(sb, kt + 2);
      sb = (sb == 2) ? 0 : sb + 1;
      if constexpr (NL == 5) asm volatile("s_waitcnt vmcnt(5)" ::: "memory");
      else                   asm volatile("s_waitcnt vmcnt(4)" ::: "memory");
    } else {
      asm volatile("s_waitcnt vmcnt(0)" ::: "memory");
    }
    __builtin_amdgcn_s_barrier();
    asm volatile("s_waitcnt lgkmcnt(0)" ::: "memory");
    __builtin_amdgcn_sched_barrier(0);
    __builtin_amdgcn_s_setprio(1);
#pragma unroll
    for (int i = 0; i < 4; ++i)
#pragma unroll
      for (int j = 0; j < NJ; ++j)
        acc[i][j] = mfma16(af[i], bf[j], acc[i][j]);
    __builtin_amdgcn_s_setprio(0);
    __builtin_amdgcn_sched_barrier(0);
    __builtin_amdgcn_s_barrier();
    cb = (cb == 2) ? 0 : cb + 1;
  }

#pragma unroll
  for (int i = 0; i < 4; ++i) {
    int rr = m0 + wm + i * 16 + hi * 4;
#pragma unroll
    for (int j = 0; j < NJ; ++j) {
      int colw = wn + j * 16 + ln;
      float sc = (EPI == 1 && colw < 64) ? 0.125f : 1.f;
      int col = n0 + colw;
#pragma unroll
      for (int r = 0; r < 4; ++r)
        store_out(&C[(size_t)(rr + r) * N + col], acc[i][j][r] * sc);
    }
  }
}

// ---------------- causal flash attention v7: merged halves + XCD KV locality --
__global__ __launch_bounds__(512, 4) void attn_fwd7(const u16* __restrict__ QKV,
                                                    const u16* __restrict__ Vt,
                                                    u16* __restrict__ O) {
  __shared__ __align__(16) u16 sK[2][4096];
  __shared__ __align__(16) u16 sVt[2][4096];
  __shared__ __align__(16) u16 sP[8][16 * 72];
  const int tid = threadIdx.x, lane = tid & 63, wid = tid >> 6;
  const int bid = blockIdx.x;
  const int w = (bid & 7) * 64 + (bid >> 3);
  const int z = w & 3, h = (w >> 2) & 15, bb = w >> 6;
  const size_t rowbase = (size_t)bb * 1024;
  const size_t vbase = ((size_t)bb * 16 + h) * 64;
  const int colQ = h * 192, colK = colQ + 64;
  const int hi = lane >> 4, ln = lane & 15;
  const int slr = lane >> 3;
  const int sle = ((lane & 7) ^ slr) * 8;
  u16* sPw = sP[wid];
  const u16x8 onesf = {0x3F80, 0x3F80, 0x3F80, 0x3F80, 0x3F80, 0x3F80, 0x3F80, 0x3F80};

  auto stageKV = [&](int buf, int nt) {
    const int n0g = nt * 64;
    gld_lds16(QKV + (rowbase + n0g + 8 * wid + slr) * 3072 + colK + sle,
              &sK[buf][wid * 512]);
    gld_lds16(Vt + (vbase + 8 * wid + slr) * 1024 + n0g + sle,
              &sVt[buf][wid * 512]);
  };

  const int mtA = z, mtB = 7 - z;
  const int qrow0A = mtA * 128 + wid * 16;
  const int qrow0B = mtB * 128 + wid * 16;
  const int ntA = 2 * mtA + 2, ntB = 2 * mtB + 2;

  u16x8 qfA[2], qfB[2];
#pragma unroll
  for (int kb = 0; kb < 2; ++kb) {
    qfA[kb] = *(const u16x8*)(QKV + (rowbase + qrow0A + ln) * 3072 + colQ + kb * 32 + hi * 8);
    qfB[kb] = *(const u16x8*)(QKV + (rowbase + qrow0B + ln) * 3072 + colQ + kb * 32 + hi * 8);
  }

  f32x4 oA[4] = {}, oB[4] = {};
  f32x4 laccA = {0.f, 0.f, 0.f, 0.f}, laccB = {0.f, 0.f, 0.f, 0.f};

  auto computeHalf = [&](const u16x8* qf, f32x4* o, f32x4& lacc, int qrow0,
                         int buf, int n0g) {
    f32x4 s[4] = {};
    __builtin_amdgcn_s_setprio(1);
#pragma unroll
    for (int kb = 0; kb < 2; ++kb)
#pragma unroll
      for (int j = 0; j < 4; ++j) {
        int row = j * 16 + ln;
        int cb = (kb * 64 + hi * 16) ^ ((row & 7) << 4);
        u16x8 kfr = *(const u16x8*)(&sK[buf][(row * 128 + cb) >> 1]);
        s[j] = mfma16(qf[kb], kfr, s[j]);
      }
    __builtin_amdgcn_s_setprio(0);
    if (n0g + 63 > qrow0) {
#pragma unroll
      for (int j = 0; j < 4; ++j) {
        int col = n0g + j * 16 + ln;
#pragma unroll
        for (int r = 0; r < 4; ++r)
          if (col > qrow0 + hi * 4 + r) s[j][r] = -3e38f;
      }
    }
#pragma unroll
    for (int j = 0; j < 4; ++j)
#pragma unroll
      for (int r = 0; r < 4; ++r)
        sPw[(hi * 4 + r) * 72 + j * 16 + ln] = f2bf(__expf(s[j][r]));
    u16x8 pf[2];
#pragma unroll
    for (int kb2 = 0; kb2 < 2; ++kb2)
      pf[kb2] = *(const u16x8*)(&sPw[ln * 72 + kb2 * 32 + hi * 8]);
    __builtin_amdgcn_s_setprio(1);
    lacc = mfma16(pf[0], onesf, lacc);
    lacc = mfma16(pf[1], onesf, lacc);
#pragma unroll
    for (int dt = 0; dt < 4; ++dt)
#pragma unroll
      for (int kb2 = 0; kb2 < 2; ++kb2) {
        int row = dt * 16 + ln;
        int cb = (kb2 * 64 + hi * 16) ^ ((row & 7) << 4);
        u16x8 vfr = *(const u16x8*)(&sVt[buf][(row * 128 + cb) >> 1]);
        o[dt] = mfma16(pf[kb2], vfr, o[dt]);
      }
    __builtin_amdgcn_s_setprio(0);
  };

  stageKV(0, 0);
  for (int nt = 0; nt < ntB; ++nt) {
    __syncthreads();
    if (nt + 1 < ntB) stageKV((nt + 1) & 1, nt + 1);
    const int buf = nt & 1;
    const int n0g = nt * 64;
    if (nt < ntA && n0g <= qrow0A + 15) computeHalf(qfA, oA, laccA, qrow0A, buf, n0g);
    if (n0g <= qrow0B + 15)             computeHalf(qfB, oB, laccB, qrow0B, buf, n0g);
  }

#pragma unroll
  for (int r = 0; r < 4; ++r) {
    float invA = 1.f / laccA[r];
    float invB = 1.f / laccB[r];
#pragma unroll
    for (int dt = 0; dt < 4; ++dt) {
      O[(rowbase + qrow0A + hi * 4 + r) * 1024 + h * 64 + dt * 16 + ln] =
          f2bf(oA[dt][r] * invA);
      O[(rowbase + qrow0B + hi * 4 + r) * 1024 + h * 64 + dt * 16 + ln] =
          f2bf(oB[dt][r] * invB);
    }
  }
}

extern "C" void kernel_launch(void* const* d_in, const int* in_sizes, int n_in,
                              void* d_out, int out_size, void* d_ws, size_t ws_size,
                              hipStream_t stream) {
  const float* x = (const float*)d_in[0];
  const float* Pi = (const float*)d_in[1];
  const float* Po = (const float*)d_in[2];
  float* y = (float*)d_out;
  char* ws = (char*)d_ws;

  u16* qkv  = (u16*)(ws);                     // 0        .. 50331648
  u16* piT  = (u16*)(ws + 50331648);          // 50331648 .. 56623104
  u16* poT  = (u16*)(ws + 56623104);          // 56623104 .. 58720256
  u16* xbf  = (u16*)(ws + 58720256);          // 58720256 .. 75497472 (dead after GEMM1)
  u16* vt   = (u16*)(ws + 75497472);          // 75497472 .. 92274688
  u16* obuf = (u16*)(ws + 58720256);          // reuses xbf slot

  prep<<<12288, 256, 0, stream>>>(x, xbf, Pi, piT, Po, poT);

  gemm_bk64<<<dim3(16, 64), 256, 0, stream>>>(xbf, piT, qkv, vt, 8192, 3072, 1024);
  attn_fwd7<<<512, 512, 0, stream>>>(qkv, vt, obuf);
  gemm_v7<float, 128, 0><<<dim3(8, 64), 256, 0, stream>>>(obuf, poT, y, nullptr,
                                                          8192, 1024, 1024);
}

// Round 25
// 128.156 us; speedup vs baseline: 1.0971x; 1.0058x over previous
//
#include <hip/hip_runtime.h>

typedef unsigned short u16;
typedef __bf16 b16x8_t __attribute__((ext_vector_type(8)));
typedef unsigned short u16x8 __attribute__((ext_vector_type(8)));
typedef float f32x4 __attribute__((ext_vector_type(4)));

__device__ __forceinline__ u16 f2bf(float f) {
  union { float f; unsigned u; } x; x.f = f;
  unsigned r = x.u + 0x7fffu + ((x.u >> 16) & 1u);
  return (u16)(r >> 16);
}

__device__ __forceinline__ f32x4 mfma16(u16x8 a, u16x8 b, f32x4 c) {
  return __builtin_amdgcn_mfma_f32_16x16x32_bf16(
      __builtin_bit_cast(b16x8_t, a), __builtin_bit_cast(b16x8_t, b), c, 0, 0, 0);
}

__device__ __forceinline__ void gld_lds16(const void* g, void* l) {
  __builtin_amdgcn_global_load_lds(
      (const __attribute__((address_space(1))) void*)g,
      (__attribute__((address_space(3))) void*)l, 16, 0, 0);
}

__device__ __forceinline__ void store_out(float* p, float v) { *p = v; }
__device__ __forceinline__ void store_out(u16* p, float v) { *p = f2bf(v); }

// ---------------- fused prep: convert x->bf16 + transpose Pi + transpose Po ---
__global__ __launch_bounds__(256) void prep(const float* __restrict__ x,
                                            u16* __restrict__ xbf,
                                            const float* __restrict__ Pi,
                                            u16* __restrict__ piT,
                                            const float* __restrict__ Po,
                                            u16* __restrict__ poT) {
  __shared__ float t[32][33];
  const int bid = blockIdx.x, tid = threadIdx.x;
  if (bid < 8192) {
    int i = bid * 256 + tid;
    float4 f = ((const float4*)x)[i];
    u16 a0 = f2bf(f.x), a1 = f2bf(f.y), a2 = f2bf(f.z), a3 = f2bf(f.w);
    unsigned lo = (unsigned)a0 | ((unsigned)a1 << 16);
    unsigned hi = (unsigned)a2 | ((unsigned)a3 << 16);
    ((uint2*)xbf)[i] = make_uint2(lo, hi);
    return;
  }
  const float* src; u16* dst; int R, Cn, bx, by;
  if (bid < 11264) {
    int tb = bid - 8192;  src = Pi; dst = piT; R = 1024; Cn = 3072;
    bx = tb % 96; by = tb / 96;
  } else {
    int tb = bid - 11264; src = Po; dst = poT; R = 1024; Cn = 1024;
    bx = tb % 32; by = tb / 32;
  }
  const int tx = tid & 31, ty = tid >> 5;
  const int c0 = bx * 32, r0 = by * 32;
  for (int j = 0; j < 32; j += 8)
    t[ty + j][tx] = src[(size_t)(r0 + ty + j) * Cn + c0 + tx];
  __syncthreads();
  for (int j = 0; j < 32; j += 8)
    dst[(size_t)(c0 + ty + j) * R + r0 + tx] = f2bf(t[tx][ty + j]);
}

// ------- bf16 GEMM BK=64 ping-pong: ONE barrier + ONE drain per K-64 tile -----
// R24-proven structure (first GEMM win in 14 attempts: total -4us). Per iter:
// stage(kt+1) issued FIRST (HBM latency hides under 2x compute window), then
// 2 k-substeps of {ds_reads -> lgkm(0)+fence -> MFMA}, then vmcnt(0) + ONE
// barrier. WAR: other-buf reads drained (lgkm0) before the barrier preceding
// its staging; RAW: per-wave vmcnt(0) precedes the shared barrier.
// Swizzle: LDS[r][c] = global[r][c^(r&7)] via pre-swizzled source; frag slot
// = (s*4+hi)^(ln&7); <=2-way bank aliasing (free, m136).
// EPI=1: Q cols x0.125; V cols written DIRECTLY TRANSPOSED to Vt.
template <typename OutT, int BN, int EPI>
__global__ __launch_bounds__(256) void gemm_bk64(const u16* __restrict__ A,
                                                 const u16* __restrict__ Bt,
                                                 OutT* __restrict__ C,
                                                 u16* __restrict__ Vt,
                                                 int M, int N, int K) {
  constexpr int NJ = BN / 32;     // per-wave N-frags (6 or 4)
  constexpr int NGB = BN / 32;    // B glds per stage (6 or 4)
  __shared__ __align__(16) u16 sA[2][8192];      // [buf][128 rows x 64 k]
  __shared__ __align__(16) u16 sB[2][BN * 64];
  const int tid = threadIdx.x, lane = tid & 63, wid = tid >> 6;
  const int hi = lane >> 4, ln = lane & 15;
  const int wm = (wid >> 1) * 64, wn = (wid & 1) * (BN / 2);

  const int gdx = gridDim.x;
  const int nwg = gdx * gridDim.y;
  int wg = blockIdx.y * gdx + blockIdx.x;
  wg = (wg & 7) * (nwg >> 3) + (wg >> 3);
  const int m0 = (wg / gdx) * 128;
  const int n0 = (wg % gdx) * BN;

  // staging: per gld covers 32 rows; row = g*32 + (tid>>3), chunk-slot tid&7;
  // source chunk pre-swizzled by row&7 (= (tid>>3)&7 since g*32 is 8-aligned)
  const int sr = tid >> 3;
  const int ssw = ((tid & 7) ^ (sr & 7)) * 8;
  const u16* srcA = A + (size_t)(m0 + sr) * K + ssw;
  const u16* srcB = Bt + (size_t)(n0 + sr) * K + ssw;
  const size_t K32 = (size_t)32 * K;

  auto stage = [&](int buf, int t) {
    const int k0 = t * 64;
#pragma unroll
    for (int g = 0; g < 4; ++g)
      gld_lds16(srcA + (size_t)g * K32 + k0, &sA[buf][g * 2048 + tid * 8]);
#pragma unroll
    for (int g = 0; g < NGB; ++g)
      gld_lds16(srcB + (size_t)g * K32 + k0, &sB[buf][g * 2048 + tid * 8]);
  };

  // fragment offsets: row*64 + ((s*4+hi) ^ (row&7))*8, row&7 == ln&7
  int offA[4][2], offB[NJ][2];
#pragma unroll
  for (int i = 0; i < 4; ++i) {
    int row = wm + i * 16 + ln;
#pragma unroll
    for (int s = 0; s < 2; ++s)
      offA[i][s] = row * 64 + (((s * 4 + hi) ^ (ln & 7)) * 8);
  }
#pragma unroll
  for (int j = 0; j < NJ; ++j) {
    int row = wn + j * 16 + ln;
#pragma unroll
    for (int s = 0; s < 2; ++s)
      offB[j][s] = row * 64 + (((s * 4 + hi) ^ (ln & 7)) * 8);
  }

  f32x4 acc[4][NJ] = {};
  const int NT = K >> 6;  // 16

  stage(0, 0);
  asm volatile("s_waitcnt vmcnt(0)" ::: "memory");
  __builtin_amdgcn_s_barrier();

  for (int kt = 0; kt < NT; ++kt) {
    const int cb = kt & 1;
    if (kt + 1 < NT) stage(cb ^ 1, kt + 1);   // early issue; latency spans iter
#pragma unroll
    for (int s = 0; s < 2; ++s) {
      u16x8 af[4], bf[NJ];
#pragma unroll
      for (int i = 0; i < 4; ++i) af[i] = *(const u16x8*)(&sA[cb][offA[i][s]]);
#pragma unroll
      for (int j = 0; j < NJ; ++j) bf[j] = *(const u16x8*)(&sB[cb][offB[j][s]]);
      asm volatile("s_waitcnt lgkmcnt(0)" ::: "memory");
      __builtin_amdgcn_sched_barrier(0);
      __builtin_amdgcn_s_setprio(1);
#pragma unroll
      for (int i = 0; i < 4; ++i)
#pragma unroll
        for (int j = 0; j < NJ; ++j)
          acc[i][j] = mfma16(af[i], bf[j], acc[i][j]);
      __builtin_amdgcn_s_setprio(0);
      __builtin_amdgcn_sched_barrier(0);
    }
    asm volatile("s_waitcnt vmcnt(0)" ::: "memory");   // tile kt+1 landed
    __builtin_amdgcn_s_barrier();                      // the ONE barrier
  }

  // epilogue: col = lane&15, row = (lane>>4)*4 + reg
#pragma unroll
  for (int i = 0; i < 4; ++i) {
    int rr = m0 + wm + i * 16 + hi * 4;
#pragma unroll
    for (int j = 0; j < NJ; ++j) {
      int colw = wn + j * 16 + ln;
      if (EPI == 1 && colw >= 128) {
        int h = n0 / 192, kk = colw - 128;
        int b = rr >> 10, n = rr & 1023;
        ushort4 pk;
        pk.x = f2bf(acc[i][j][0]); pk.y = f2bf(acc[i][j][1]);
        pk.z = f2bf(acc[i][j][2]); pk.w = f2bf(acc[i][j][3]);
        *(ushort4*)(Vt + ((size_t)(b * 16 + h) * 64 + kk) * 1024 + n) = pk;
      } else {
        float sc = (EPI == 1 && colw < 64) ? 0.125f : 1.f;
        int col = n0 + colw;
#pragma unroll
        for (int r = 0; r < 4; ++r)
          store_out(&C[(size_t)(rr + r) * N + col], acc[i][j][r] * sc);
      }
    }
  }
}

// ---------------- causal flash attention v7: merged halves + XCD KV locality --
__global__ __launch_bounds__(512, 4) void attn_fwd7(const u16* __restrict__ QKV,
                                                    const u16* __restrict__ Vt,
                                                    u16* __restrict__ O) {
  __shared__ __align__(16) u16 sK[2][4096];
  __shared__ __align__(16) u16 sVt[2][4096];
  __shared__ __align__(16) u16 sP[8][16 * 72];
  const int tid = threadIdx.x, lane = tid & 63, wid = tid >> 6;
  const int bid = blockIdx.x;
  const int w = (bid & 7) * 64 + (bid >> 3);
  const int z = w & 3, h = (w >> 2) & 15, bb = w >> 6;
  const size_t rowbase = (size_t)bb * 1024;
  const size_t vbase = ((size_t)bb * 16 + h) * 64;
  const int colQ = h * 192, colK = colQ + 64;
  const int hi = lane >> 4, ln = lane & 15;
  const int slr = lane >> 3;
  const int sle = ((lane & 7) ^ slr) * 8;
  u16* sPw = sP[wid];
  const u16x8 onesf = {0x3F80, 0x3F80, 0x3F80, 0x3F80, 0x3F80, 0x3F80, 0x3F80, 0x3F80};

  auto stageKV = [&](int buf, int nt) {
    const int n0g = nt * 64;
    gld_lds16(QKV + (rowbase + n0g + 8 * wid + slr) * 3072 + colK + sle,
              &sK[buf][wid * 512]);
    gld_lds16(Vt + (vbase + 8 * wid + slr) * 1024 + n0g + sle,
              &sVt[buf][wid * 512]);
  };

  const int mtA = z, mtB = 7 - z;
  const int qrow0A = mtA * 128 + wid * 16;
  const int qrow0B = mtB * 128 + wid * 16;
  const int ntA = 2 * mtA + 2, ntB = 2 * mtB + 2;

  u16x8 qfA[2], qfB[2];
#pragma unroll
  for (int kb = 0; kb < 2; ++kb) {
    qfA[kb] = *(const u16x8*)(QKV + (rowbase + qrow0A + ln) * 3072 + colQ + kb * 32 + hi * 8);
    qfB[kb] = *(const u16x8*)(QKV + (rowbase + qrow0B + ln) * 3072 + colQ + kb * 32 + hi * 8);
  }

  f32x4 oA[4] = {}, oB[4] = {};
  f32x4 laccA = {0.f, 0.f, 0.f, 0.f}, laccB = {0.f, 0.f, 0.f, 0.f};

  auto computeHalf = [&](const u16x8* qf, f32x4* o, f32x4& lacc, int qrow0,
                         int buf, int n0g) {
    f32x4 s[4] = {};
    __builtin_amdgcn_s_setprio(1);
#pragma unroll
    for (int kb = 0; kb < 2; ++kb)
#pragma unroll
      for (int j = 0; j < 4; ++j) {
        int row = j * 16 + ln;
        int cb = (kb * 64 + hi * 16) ^ ((row & 7) << 4);
        u16x8 kfr = *(const u16x8*)(&sK[buf][(row * 128 + cb) >> 1]);
        s[j] = mfma16(qf[kb], kfr, s[j]);
      }
    __builtin_amdgcn_s_setprio(0);
    if (n0g + 63 > qrow0) {
#pragma unroll
      for (int j = 0; j < 4; ++j) {
        int col = n0g + j * 16 + ln;
#pragma unroll
        for (int r = 0; r < 4; ++r)
          if (col > qrow0 + hi * 4 + r) s[j][r] = -3e38f;
      }
    }
#pragma unroll
    for (int j = 0; j < 4; ++j)
#pragma unroll
      for (int r = 0; r < 4; ++r)
        sPw[(hi * 4 + r) * 72 + j * 16 + ln] = f2bf(__expf(s[j][r]));
    u16x8 pf[2];
#pragma unroll
    for (int kb2 = 0; kb2 < 2; ++kb2)
      pf[kb2] = *(const u16x8*)(&sPw[ln * 72 + kb2 * 32 + hi * 8]);
    __builtin_amdgcn_s_setprio(1);
    lacc = mfma16(pf[0], onesf, lacc);
    lacc = mfma16(pf[1], onesf, lacc);
#pragma unroll
    for (int dt = 0; dt < 4; ++dt)
#pragma unroll
      for (int kb2 = 0; kb2 < 2; ++kb2) {
        int row = dt * 16 + ln;
        int cb = (kb2 * 64 + hi * 16) ^ ((row & 7) << 4);
        u16x8 vfr = *(const u16x8*)(&sVt[buf][(row * 128 + cb) >> 1]);
        o[dt] = mfma16(pf[kb2], vfr, o[dt]);
      }
    __builtin_amdgcn_s_setprio(0);
  };

  stageKV(0, 0);
  for (int nt = 0; nt < ntB; ++nt) {
    __syncthreads();
    if (nt + 1 < ntB) stageKV((nt + 1) & 1, nt + 1);
    const int buf = nt & 1;
    const int n0g = nt * 64;
    if (nt < ntA && n0g <= qrow0A + 15) computeHalf(qfA, oA, laccA, qrow0A, buf, n0g);
    if (n0g <= qrow0B + 15)             computeHalf(qfB, oB, laccB, qrow0B, buf, n0g);
  }

#pragma unroll
  for (int r = 0; r < 4; ++r) {
    float invA = 1.f / laccA[r];
    float invB = 1.f / laccB[r];
#pragma unroll
    for (int dt = 0; dt < 4; ++dt) {
      O[(rowbase + qrow0A + hi * 4 + r) * 1024 + h * 64 + dt * 16 + ln] =
          f2bf(oA[dt][r] * invA);
      O[(rowbase + qrow0B + hi * 4 + r) * 1024 + h * 64 + dt * 16 + ln] =
          f2bf(oB[dt][r] * invB);
    }
  }
}

extern "C" void kernel_launch(void* const* d_in, const int* in_sizes, int n_in,
                              void* d_out, int out_size, void* d_ws, size_t ws_size,
                              hipStream_t stream) {
  const float* x = (const float*)d_in[0];
  const float* Pi = (const float*)d_in[1];
  const float* Po = (const float*)d_in[2];
  float* y = (float*)d_out;
  char* ws = (char*)d_ws;

  u16* qkv  = (u16*)(ws);                     // 0        .. 50331648
  u16* piT  = (u16*)(ws + 50331648);          // 50331648 .. 56623104
  u16* poT  = (u16*)(ws + 56623104);          // 56623104 .. 58720256
  u16* xbf  = (u16*)(ws + 58720256);          // 58720256 .. 75497472 (dead after GEMM1)
  u16* vt   = (u16*)(ws + 75497472);          // 75497472 .. 92274688
  u16* obuf = (u16*)(ws + 58720256);          // reuses xbf slot

  prep<<<12288, 256, 0, stream>>>(x, xbf, Pi, piT, Po, poT);

  gemm_bk64<u16, 192, 1><<<dim3(16, 64), 256, 0, stream>>>(xbf, piT, qkv, vt,
                                                           8192, 3072, 1024);
  attn_fwd7<<<512, 512, 0, stream>>>(qkv, vt, obuf);
  gemm_bk64<float, 128, 0><<<dim3(8, 64), 256, 0, stream>>>(obuf, poT, y, nullptr,
                                                            8192, 1024, 1024);
}